// Round 1
// baseline (361.646 us; speedup 1.0000x reference)
//
#include <hip/hip_runtime.h>

typedef __bf16 bf16x8 __attribute__((ext_vector_type(8)));
typedef float  f32x4  __attribute__((ext_vector_type(4)));
typedef unsigned int u32x4 __attribute__((ext_vector_type(4)));

#define B_   2
#define N_   512
#define ND_  256
#define ED_  64
#define NH_  8
#define DH_  32

static __device__ __forceinline__ unsigned pack_bf16(float a, float b) {
    unsigned short ua = __builtin_bit_cast(unsigned short, (__bf16)a);
    unsigned short ub = __builtin_bit_cast(unsigned short, (__bf16)b);
    return (unsigned)ua | ((unsigned)ub << 16);
}

// ---------------- prep kernel 1: edge-weight fp32 -> bf16 ----------------
// W16 layout: [3][256][64] (m, n=out, k=in) — exactly W's own [out][in] layout.
__global__ __launch_bounds__(256) void cvt_w_kernel(
    const float* __restrict__ wq, const float* __restrict__ wk,
    const float* __restrict__ wv, unsigned short* __restrict__ w16)
{
    int id = blockIdx.x * 256 + threadIdx.x;          // 0..49151
    const float* src = (id < 16384) ? wq : (id < 32768 ? wk : wv);
    int idx = id & 16383;
    w16[id] = __builtin_bit_cast(unsigned short, (__bf16)src[idx]);
}

// ---------------- prep kernel 2: node projections with folded biases -----
// Q = node@Wnq^T + bnq + beq ; K = node@Wnk^T + bnk + bek ; V = node@Wnv^T + bnv + bev
__global__ __launch_bounds__(256) void qkv_kernel(
    const float* __restrict__ node,
    const float* __restrict__ Wq, const float* __restrict__ bq,
    const float* __restrict__ Wk, const float* __restrict__ bk,
    const float* __restrict__ Wv, const float* __restrict__ bv,
    const float* __restrict__ beq, const float* __restrict__ bek,
    const float* __restrict__ bev,
    float* __restrict__ Q, float* __restrict__ K, float* __restrict__ V)
{
    __shared__ float xs[8][ND_];
    const int c  = threadIdx.x;                // output column 0..255
    const int g0 = blockIdx.x * 8;             // 8 rows of [B*N] per block
    #pragma unroll
    for (int rr = 0; rr < 8; rr++) xs[rr][c] = node[(size_t)(g0 + rr) * ND_ + c];
    __syncthreads();

    float aq[8] = {}, ak[8] = {}, av[8] = {};
    const float4* wqr = reinterpret_cast<const float4*>(Wq + (size_t)c * ND_);
    const float4* wkr = reinterpret_cast<const float4*>(Wk + (size_t)c * ND_);
    const float4* wvr = reinterpret_cast<const float4*>(Wv + (size_t)c * ND_);
    for (int k4 = 0; k4 < ND_ / 4; k4++) {
        float4 wqv = wqr[k4], wkv = wkr[k4], wvv = wvr[k4];
        #pragma unroll
        for (int rr = 0; rr < 8; rr++) {
            const float* x = &xs[rr][k4 * 4];
            aq[rr] += x[0]*wqv.x + x[1]*wqv.y + x[2]*wqv.z + x[3]*wqv.w;
            ak[rr] += x[0]*wkv.x + x[1]*wkv.y + x[2]*wkv.z + x[3]*wkv.w;
            av[rr] += x[0]*wvv.x + x[1]*wvv.y + x[2]*wvv.z + x[3]*wvv.w;
        }
    }
    float bqv = bq[c] + beq[c];
    float bkv = bk[c] + bek[c];
    float bvv = bv[c] + bev[c];
    #pragma unroll
    for (int rr = 0; rr < 8; rr++) {
        size_t o = (size_t)(g0 + rr) * ND_ + c;
        Q[o] = aq[rr] + bqv;
        K[o] = ak[rr] + bkv;
        V[o] = av[rr] + bvv;
    }
}

// ---------------- main fused kernel: one block per (b,i) -----------------
// 8 waves / block, wave w = head w. Flash-style online softmax over j.
__global__ __launch_bounds__(512) void attn_kernel(
    const float* __restrict__ edge,
    const float* __restrict__ Q, const float* __restrict__ K,
    const float* __restrict__ V, const unsigned short* __restrict__ W16,
    float* __restrict__ out)
{
    // e-tile: 16 rows (j) x 64 cols (k) bf16, row stride 72 shorts (16B-aligned rows)
    __shared__ unsigned short smem[16 * 72];

    const int tid  = threadIdx.x;
    const int lane = tid & 63;
    const int w    = tid >> 6;       // wave id == head
    const int q4   = lane >> 4;      // quad
    const int l15  = lane & 15;
    const int blk  = blockIdx.x;
    const int b    = blk >> 9;
    const int i    = blk & (N_ - 1);

    // persistent B-frags: wf[m][nt][ks], m in {q,k,v}, nt = 16-wide n-tile, ks = 32-wide K-step
    // B-frag lane layout: B[k = q4*8 + jj][n = nt*16 + l15]; from W16[m][n][k] row-major.
    bf16x8 wf[3][2][2];
    #pragma unroll
    for (int m = 0; m < 3; m++)
        #pragma unroll
        for (int nt = 0; nt < 2; nt++)
            #pragma unroll
            for (int ks = 0; ks < 2; ks++) {
                int n = w * DH_ + nt * 16 + l15;
                const u32x4* p = reinterpret_cast<const u32x4*>(
                    W16 + m * (ND_ * ED_) + n * ED_ + ks * 32 + q4 * 8);
                wf[m][nt][ks] = __builtin_bit_cast(bf16x8, *p);
            }

    const float* Qrow = Q + (size_t)(b * N_ + i) * ND_ + w * DH_;
    float Qv0 = Qrow[l15];
    float Qv1 = Qrow[16 + l15];
    const float* Kb = K + (size_t)b * N_ * ND_ + w * DH_ + l15;
    const float* Vb = V + (size_t)b * N_ * ND_ + w * DH_ + l15;
    const float* ebase = edge + (size_t)blk * N_ * ED_;

    float m_run = -INFINITY, l_run = 0.f;
    float o0 = 0.f, o1 = 0.f;
    const float scale = 0.17677669529663687f;   // 1/sqrt(32)

    #pragma unroll 1
    for (int jt = 0; jt < N_ / 16; jt++) {
        const int jb = jt * 16;
        __syncthreads();
        {   // stage e[b,i, jb..jb+16, 0..64) -> LDS bf16 (1024 floats, 512 thr x float2)
            const float2 g = reinterpret_cast<const float2*>(ebase + jb * ED_)[tid];
            reinterpret_cast<unsigned*>(smem)[(tid >> 5) * 36 + (tid & 31)] =
                pack_bf16(g.x, g.y);
        }
        __syncthreads();

        // A-frags (shared by eq/ek/ev): A[m=l15][k=q4*8+jj (+32 for ks=1)]
        const unsigned short* arow = smem + l15 * 72 + q4 * 8;
        bf16x8 a0 = __builtin_bit_cast(bf16x8, *reinterpret_cast<const u32x4*>(arow));
        bf16x8 a1 = __builtin_bit_cast(bf16x8, *reinterpret_cast<const u32x4*>(arow + 32));

        // K/V for this tile: lane needs rows j = jb + q4*4 + r, cols w*32 + nt*16 + l15
        float Kv0[4], Kv1[4], Vv0[4], Vv1[4];
        #pragma unroll
        for (int r = 0; r < 4; r++) {
            const int j = jb + q4 * 4 + r;
            const float* kr = Kb + (size_t)j * ND_;
            const float* vr = Vb + (size_t)j * ND_;
            Kv0[r] = kr[0];  Kv1[r] = kr[16];
            Vv0[r] = vr[0];  Vv1[r] = vr[16];
        }

        // projections for this head chunk: [16 j] x [32 n]
        f32x4 z = {0.f, 0.f, 0.f, 0.f};
        f32x4 eq0 = __builtin_amdgcn_mfma_f32_16x16x32_bf16(a0, wf[0][0][0], z, 0, 0, 0);
        f32x4 eq1 = __builtin_amdgcn_mfma_f32_16x16x32_bf16(a0, wf[0][1][0], z, 0, 0, 0);
        f32x4 ek0 = __builtin_amdgcn_mfma_f32_16x16x32_bf16(a0, wf[1][0][0], z, 0, 0, 0);
        f32x4 ek1 = __builtin_amdgcn_mfma_f32_16x16x32_bf16(a0, wf[1][1][0], z, 0, 0, 0);
        f32x4 ev0 = __builtin_amdgcn_mfma_f32_16x16x32_bf16(a0, wf[2][0][0], z, 0, 0, 0);
        f32x4 ev1 = __builtin_amdgcn_mfma_f32_16x16x32_bf16(a0, wf[2][1][0], z, 0, 0, 0);
        eq0 = __builtin_amdgcn_mfma_f32_16x16x32_bf16(a1, wf[0][0][1], eq0, 0, 0, 0);
        eq1 = __builtin_amdgcn_mfma_f32_16x16x32_bf16(a1, wf[0][1][1], eq1, 0, 0, 0);
        ek0 = __builtin_amdgcn_mfma_f32_16x16x32_bf16(a1, wf[1][0][1], ek0, 0, 0, 0);
        ek1 = __builtin_amdgcn_mfma_f32_16x16x32_bf16(a1, wf[1][1][1], ek1, 0, 0, 0);
        ev0 = __builtin_amdgcn_mfma_f32_16x16x32_bf16(a1, wf[2][0][1], ev0, 0, 0, 0);
        ev1 = __builtin_amdgcn_mfma_f32_16x16x32_bf16(a1, wf[2][1][1], ev1, 0, 0, 0);

        // scores: s[h][j] = sum_n (eq + Q)(ek + K); C/D layout: reg r -> j=q4*4+r, col=l15
        float s[4];
        #pragma unroll
        for (int r = 0; r < 4; r++) {
            float t = (eq0[r] + Qv0) * (ek0[r] + Kv0[r])
                    + (eq1[r] + Qv1) * (ek1[r] + Kv1[r]);
            t += __shfl_xor(t, 1, 64);
            t += __shfl_xor(t, 2, 64);
            t += __shfl_xor(t, 4, 64);
            t += __shfl_xor(t, 8, 64);
            s[r] = t * scale;
        }
        float tmax = fmaxf(fmaxf(s[0], s[1]), fmaxf(s[2], s[3]));
        tmax = fmaxf(tmax, __shfl_xor(tmax, 16, 64));
        tmax = fmaxf(tmax, __shfl_xor(tmax, 32, 64));
        const float m_new = fmaxf(m_run, tmax);
        const float alpha = __expf(m_run - m_new);
        float p[4], psum = 0.f;
        #pragma unroll
        for (int r = 0; r < 4; r++) { p[r] = __expf(s[r] - m_new); psum += p[r]; }
        psum += __shfl_xor(psum, 16, 64);
        psum += __shfl_xor(psum, 32, 64);
        l_run = l_run * alpha + psum;
        m_run = m_new;

        float acc0 = 0.f, acc1 = 0.f;
        #pragma unroll
        for (int r = 0; r < 4; r++) {
            acc0 += p[r] * (ev0[r] + Vv0[r]);
            acc1 += p[r] * (ev1[r] + Vv1[r]);
        }
        o0 = o0 * alpha + acc0;
        o1 = o1 * alpha + acc1;
    }

    // combine quads (each quad covered a disjoint j subset, same m/l trajectory)
    o0 += __shfl_xor(o0, 16, 64);  o0 += __shfl_xor(o0, 32, 64);
    o1 += __shfl_xor(o1, 16, 64);  o1 += __shfl_xor(o1, 32, 64);
    const float inv = 1.f / l_run;
    if (q4 == 0) {
        float* orow = out + (size_t)(b * N_ + i) * ND_ + w * DH_;
        orow[l15]      = o0 * inv;
        orow[16 + l15] = o1 * inv;
    }
}

extern "C" void kernel_launch(void* const* d_in, const int* in_sizes, int n_in,
                              void* d_out, int out_size, void* d_ws, size_t ws_size,
                              hipStream_t stream) {
    const float* node = (const float*)d_in[0];
    const float* edge = (const float*)d_in[1];
    const float* Wnq  = (const float*)d_in[2];
    const float* bnq  = (const float*)d_in[3];
    const float* Wnk  = (const float*)d_in[4];
    const float* bnk  = (const float*)d_in[5];
    const float* Wnv  = (const float*)d_in[6];
    const float* bnv  = (const float*)d_in[7];
    const float* Weq  = (const float*)d_in[8];
    const float* beq  = (const float*)d_in[9];
    const float* Wek  = (const float*)d_in[10];
    const float* bek  = (const float*)d_in[11];
    const float* Wev  = (const float*)d_in[12];
    const float* bev  = (const float*)d_in[13];

    char* ws = (char*)d_ws;
    unsigned short* W16 = (unsigned short*)ws;              // 3*256*64*2 = 96 KB
    float* Q = (float*)(ws + 131072);                       // 1 MB each
    float* K = Q + (size_t)B_ * N_ * ND_;
    float* V = K + (size_t)B_ * N_ * ND_;
    float* out = (float*)d_out;

    cvt_w_kernel<<<192, 256, 0, stream>>>(Weq, Wek, Wev, W16);
    qkv_kernel<<<(B_ * N_) / 8, 256, 0, stream>>>(node, Wnq, bnq, Wnk, bnk, Wnv, bnv,
                                                  beq, bek, bev, Q, K, V);
    attn_kernel<<<B_ * N_, 512, 0, stream>>>(edge, Q, K, V, W16, out);
}